// Round 12
// baseline (138.129 us; speedup 1.0000x reference)
//
#include <hip/hip_runtime.h>

// Problem constants
constexpr int NK    = 625;
constexpr int WPADR = 132;     // reference padded width
constexpr int IMG   = 8;       // images per block (weight amortization)
constexpr int NSLAB = 5;       // 125 outputs per slab
constexpr size_t WGF_FLOATS = (size_t)40 * NK * 4;   // 100000 floats = 400 KB

// ---- gather: dense W -> f32 weights, zero-padded 16-slot rows, transposed ----
// wgf as float4[40][625]: j = half*20 + p*4 + q holds slots s=4q..4q+3 of row p
// for the (k, half) thread. Row/col alignment AND image-edge clamps are folded
// into zero slots:
//   rowbase(k,h) = max(0, 5*ki-2+5h)       (only ki=0,h=0 clamps)
//   colbase(k)   = min(112, max(0,5*kj-2) & ~3)  (kj=0 left edge, kj=24 right)
// slot (p,s) multiplies x[rowbase+p][colbase+s]; weight nonzero iff it maps to
// a real (di,dj) owned by this half.
__global__ void gather_wf(const float* __restrict__ W, float* __restrict__ wgf) {
    int t = blockIdx.x * 256 + threadIdx.x;
    if (t >= NK * 160) return;
    int k = t / 160, rem = t % 160;
    int half = rem / 80, p = (rem >> 4) % 5, s = rem & 15;
    int ki = k / 25, kj = k % 25;
    int rowbase = max(0, 5 * ki - 2 + 5 * half);
    int colbase = min(112, max(0, 5 * kj - 2) & ~3);
    int r = rowbase + p, c = colbase + s;
    int di = r - (5 * ki - 2), dj = c - (5 * kj - 2);
    float val = 0.f;
    if (di >= 5 * half && di < 5 * half + 5 && dj >= 0 && dj < 10)
        val = W[(size_t)((5 * ki + di) * WPADR + (5 * kj + dj)) * NK + k];
    wgf[((size_t)(half * 20 + p * 4 + (s >> 2)) * NK + k) * 4 + (s & 3)] = val;
}

// Block = (8-image group, 125-k slab). NO LDS, NO BARRIERS: each thread reads
// its 5 rows x 16-float aligned windows straight from global (15 KB/block-image
// working set -> L1-resident; adjacent kj windows share lines). Output k split
// across lane pair (l, l^32): half 0 = rows rowbase(h0)..+4, half 1 = +5 rows;
// combined with one __shfl_xor. Weights: 20 coalesced float4, once per block,
// reused for 8 images. Waves free-run -> latency hiding without barrier drains
// (R9-R11's stage->barrier structure plateaued at ~25 us).
template <bool USE_WG>
__global__ __launch_bounds__(256, 3)
void lc2d_direct(const float* __restrict__ x, const float* __restrict__ wgf,
                 const float* __restrict__ Wfull, const float* __restrict__ bias,
                 float* __restrict__ out) {
    const int grp  = blockIdx.x;          // 128 image groups
    const int slab = blockIdx.y;          // 5 k-slabs
    const int K0   = slab * 125;
    const int tid  = threadIdx.x;
    const int lane = tid & 63;
    const int pair = (tid >> 6) * 32 + (lane & 31);   // 0..127 (125 used)
    const int half = (lane >> 5) & 1;
    const bool active = pair < 125;
    const int pc = active ? pair : 124;   // clamp idle pairs to a valid k
    const int k  = K0 + pc;
    const int ki = k / 25, kj = k % 25;
    const int rowbase = max(0, 5 * ki - 2 + 5 * half);
    const int colbase = min(112, max(0, 5 * kj - 2) & ~3);

    // ---- weights: 20 coalesced float4 per thread, ONCE per block ----
    float4 wq[20];
    if (USE_WG) {
        const float4* wg4 = reinterpret_cast<const float4*>(wgf);
#pragma unroll
        for (int j = 0; j < 20; ++j)
            wq[j] = wg4[(size_t)(half * 20 + j) * NK + k];
    } else {
#pragma unroll
        for (int j = 0; j < 20; ++j) {
            const int p = j >> 2, q = j & 3;
            float vv[4];
#pragma unroll
            for (int m = 0; m < 4; ++m) {
                const int s = q * 4 + m;
                const int r = rowbase + p, c = colbase + s;
                const int di = r - (5 * ki - 2), dj = c - (5 * kj - 2);
                float val = 0.f;
                if (di >= 5 * half && di < 5 * half + 5 && dj >= 0 && dj < 10)
                    val = Wfull[(size_t)((5 * ki + di) * WPADR + (5 * kj + dj)) * NK + k];
                vv[m] = val;
            }
            wq[j] = make_float4(vv[0], vv[1], vv[2], vv[3]);
        }
    }
    const float bval = bias[k];

    // 16B-aligned thread base (colbase mult of 4); rows via immediate offsets
    const float* xb = x + ((size_t)(grp * IMG) << 14) + (rowbase << 7) + colbase;

    for (int i = 0; i < IMG; ++i) {
        float acc0 = 0.f, acc1 = 0.f;
#pragma unroll
        for (int p = 0; p < 5; ++p) {
            const float* rp = xb + (p << 7);
            const float4 f0 = *reinterpret_cast<const float4*>(rp);
            const float4 f1 = *reinterpret_cast<const float4*>(rp + 4);
            const float4 f2 = *reinterpret_cast<const float4*>(rp + 8);
            const float4 f3 = *reinterpret_cast<const float4*>(rp + 12);
            const float4 wA = wq[p * 4], wB = wq[p * 4 + 1];
            const float4 wC = wq[p * 4 + 2], wD = wq[p * 4 + 3];
            acc0 += f0.x * wA.x; acc1 += f0.y * wA.y;
            acc0 += f0.z * wA.z; acc1 += f0.w * wA.w;
            acc0 += f1.x * wB.x; acc1 += f1.y * wB.y;
            acc0 += f1.z * wB.z; acc1 += f1.w * wB.w;
            acc0 += f2.x * wC.x; acc1 += f2.y * wC.y;
            acc0 += f2.z * wC.z; acc1 += f2.w * wC.w;
            acc0 += f3.x * wD.x; acc1 += f3.y * wD.y;
            acc0 += f3.z * wD.z; acc1 += f3.w * wD.w;
        }
        const float r = acc0 + acc1;
        const float other = __shfl_xor(r, 32, 64);   // partner half's 5 rows
        if (active && half == 0)
            out[(size_t)(grp * IMG + i) * NK + k] = r + other + bval;
        xb += 16384;
    }
}

extern "C" void kernel_launch(void* const* d_in, const int* in_sizes, int n_in,
                              void* d_out, int out_size, void* d_ws, size_t ws_size,
                              hipStream_t stream) {
    const float* x    = (const float*)d_in[0];
    const float* W    = (const float*)d_in[1];
    const float* bias = (const float*)d_in[2];
    float* out = (float*)d_out;

    const dim3 grid(1024 / IMG, NSLAB);   // 128 x 5 = 640 blocks
    if (ws_size >= WGF_FLOATS * sizeof(float)) {
        float* wgf = (float*)d_ws;
        gather_wf<<<(NK * 160 + 255) / 256, 256, 0, stream>>>(W, wgf);
        lc2d_direct<true><<<grid, 256, 0, stream>>>(x, wgf, W, bias, out);
    } else {
        lc2d_direct<false><<<grid, 256, 0, stream>>>(x, nullptr, W, bias, out);
    }
}

// Round 13
// 126.219 us; speedup vs baseline: 1.0944x; 1.0944x over previous
//
#include <hip/hip_runtime.h>

typedef _Float16 f16x2 __attribute__((ext_vector_type(2)));
typedef __fp16  fp16x2 __attribute__((ext_vector_type(2)));

// Problem constants
constexpr int NKW  = 25, NK = 625;
constexpr int WPADR = 132;                  // reference padded width
constexpr int WPT   = 160;                  // padded halves per (ki,kj) weight row
constexpr int IMG   = 8;                    // images per wave (weight reuse)

union U2H { unsigned int u; f16x2 h; fp16x2 p; };

// ---- gather: dense W -> f16 weights, zero-padded 16-slot rows, TRANSPOSED ----
// wgpT as uint4[20][625]; slot j of output k holds padded halves 8j..8j+7.
// Real data at in-row slot o..o+9, o = (5*kj+2) & 3, matching aligned LDS
// window h0 = (5*kj+2) & ~3 (LDS half hh maps to data col hh-4).
__global__ void gather_wp(const float* __restrict__ W, _Float16* __restrict__ wgpT) {
    int t = blockIdx.x * 256 + threadIdx.x;
    if (t >= NK * WPT) return;
    int k = t / WPT, p = t % WPT;
    int di = p >> 4, s = p & 15;
    int ki = k / NKW, kj = k % NKW;
    int o = (5 * kj + 2) & 3;
    int j = s - o;
    float val = 0.f;
    if (j >= 0 && j < 10)
        val = W[(size_t)((ki * 5 + di) * WPADR + kj * 5 + j) * NK + k];
    wgpT[((size_t)(p >> 3) * NK + k) * 8 + (p & 7)] = (_Float16)val;
}

__device__ __forceinline__ float dot2acc(unsigned int a, unsigned int b, float c) {
    U2H ua, ub; ua.u = a; ub.u = b;
#if __has_builtin(__builtin_amdgcn_fdot2)
    return __builtin_amdgcn_fdot2(ua.h, ub.h, c, false);
#else
    return c + (float)ua.h.x * (float)ub.h.x + (float)ua.h.y * (float)ub.h.y;
#endif
}

// BARRIER-FREE: wave = (ki, 8-image group), private LDS double-buffer.
// R12 insight: the compiler drains vmcnt(0) before every s_barrier, which
// nullified R9-R11's software pipelines. Here each wave stages its OWN
// 10-row band (intra-wave vmcnt/lgkmcnt deps only, partial waits), so
// prefetch loads stay in flight across images and waves free-run.
// Output k split across lane pair (l, l^32): half h owns di rows 5h..5h+4,
// combined with one __shfl_xor. Weights: 10 coalesced uint4/lane, once/wave.
template <bool USE_WG>
__global__ __launch_bounds__(256, 4)
void lc2d_wave(const float* __restrict__ x, const _Float16* __restrict__ wgpT,
               const float* __restrict__ Wfull,
               const float* __restrict__ bias, float* __restrict__ out) {
    __shared__ uint2 xsw[4][2][350];        // per wave: 2 bufs x 10 rows x 35 u2 (22.4 KB)

    const int widx = threadIdx.x >> 6;
    const int lane = threadIdx.x & 63;
    const int waveId = blockIdx.x * 4 + widx;
    const int ki  = waveId % 25;
    const int grp = waveId / 25;            // 0..127
    const int b0  = grp * IMG;
    const int half = lane >> 5;
    const int p    = lane & 31;
    const int pc   = min(p, 24);            // idle pairs clamp to kj=24 (valid addrs)
    const int k    = ki * NKW + pc;
    const int di0  = half * 5;
    const int row0 = 5 * ki - 2;            // unpadded row of band row 0

    // ---- zero boundary u2 (q=0: halves 0-3 incl. left pad; q=33: right pad) ----
    if (lane < 40) {
        const int bz = lane / 20, rem = lane % 20;
        xsw[widx][bz][(rem >> 1) * 35 + (rem & 1) * 33] = make_uint2(0u, 0u);
    }

    // ---- weights: 10 coalesced uint4 per lane, ONCE per wave ----
    uint4 wq[10];
    if (USE_WG) {
        const uint4* wt4 = reinterpret_cast<const uint4*>(wgpT);
#pragma unroll
        for (int j = 0; j < 10; ++j) wq[j] = wt4[(size_t)(half * 10 + j) * NK + k];
    } else {
        const int o = (5 * pc + 2) & 3;
#pragma unroll
        for (int j = 0; j < 10; ++j) {
            const int di = di0 + (j >> 1), pb = (j & 1) * 8;
            unsigned int uu[4];
#pragma unroll
            for (int m = 0; m < 4; ++m) {
                float f0 = 0.f, f1 = 0.f;
                const int j0 = pb + 2 * m - o, j1 = pb + 2 * m + 1 - o;
                const size_t rowb = (size_t)((ki * 5 + di) * WPADR + pc * 5);
                if (j0 >= 0 && j0 < 10) f0 = Wfull[(rowb + j0) * NK + k];
                if (j1 >= 0 && j1 < 10) f1 = Wfull[(rowb + j1) * NK + k];
                U2H u; u.p = __builtin_amdgcn_cvt_pkrtz(f0, f1);
                uu[m] = u.u;
            }
            wq[j] = make_uint4(uu[0], uu[1], uu[2], uu[3]);
        }
    }
    const float bval = (half == 0) ? bias[k] : 0.f;

    // ---- per-wave pipeline phases (10 rows x 32 quads = 5 float4 per lane) ----
    auto stage_load = [&](int img, float4* tmp) {
        const float* xb = x + ((size_t)(b0 + img) << 14);
#pragma unroll
        for (int t = 0; t < 5; ++t) {
            const int i = lane + (t << 6);  // 0..319
            const int r = row0 + (i >> 5), q = i & 31;
            tmp[t] = make_float4(0.f, 0.f, 0.f, 0.f);
            if (r >= 0)                     // r < 128 always
                tmp[t] = *reinterpret_cast<const float4*>(xb + (r << 7) + (q << 2));
        }
    };
    auto stage_write = [&](int buf, const float4* tmp) {
        uint2* xd = &xsw[widx][buf][0];
#pragma unroll
        for (int t = 0; t < 5; ++t) {
            const int i = lane + (t << 6);
            const int idx = i >> 5, q = (i & 31) + 1;
            U2H u0, u1;
            u0.p = __builtin_amdgcn_cvt_pkrtz(tmp[t].x, tmp[t].y);
            u1.p = __builtin_amdgcn_cvt_pkrtz(tmp[t].z, tmp[t].w);
            xd[idx * 35 + q] = make_uint2(u0.u, u1.u);
        }
    };

    float4 tA[5], tB[5];
    stage_load(0, tA);
    stage_write(0, tA);                     // waits vmcnt on tA only
    stage_load(1, tB);                      // img1 loads in flight

    const int woff = (5 * pc + 2) >> 2;     // aligned u2 window base
    for (int i = 0; i < IMG; ++i) {
        if (i + 2 < IMG) stage_load(i + 2, (i & 1) ? tB : tA);   // reuse freed tmp

        const uint2* base = &xsw[widx][i & 1][0] + di0 * 35 + woff;
        float acc0 = 0.f, acc1 = 0.f;
#pragma unroll
        for (int d = 0; d < 5; ++d) {
            const uint2* rowp = base + d * 35;
            const uint2 a0 = rowp[0], a1 = rowp[1], a2 = rowp[2], a3 = rowp[3];
            const uint4 wA = wq[2 * d], wB = wq[2 * d + 1];
            acc0 = dot2acc(a0.x, wA.x, acc0);
            acc1 = dot2acc(a0.y, wA.y, acc1);
            acc0 = dot2acc(a1.x, wA.z, acc0);
            acc1 = dot2acc(a1.y, wA.w, acc1);
            acc0 = dot2acc(a2.x, wB.x, acc0);
            acc1 = dot2acc(a2.y, wB.y, acc1);
            acc0 = dot2acc(a3.x, wB.z, acc0);
            acc1 = dot2acc(a3.y, wB.w, acc1);
        }
        const float r = acc0 + acc1;
        const float other = __shfl_xor(r, 32, 64);
        if (half == 0 && p < 25)
            out[(size_t)(b0 + i) * NK + k] = r + other + bval;

        // write img i+1 into the other buffer; waits only its own (older) loads
        if (i + 1 < IMG) stage_write((i + 1) & 1, (i & 1) ? tA : tB);
    }
}

extern "C" void kernel_launch(void* const* d_in, const int* in_sizes, int n_in,
                              void* d_out, int out_size, void* d_ws, size_t ws_size,
                              hipStream_t stream) {
    const float* x    = (const float*)d_in[0];
    const float* W    = (const float*)d_in[1];
    const float* bias = (const float*)d_in[2];
    float* out = (float*)d_out;

    const dim3 grid(800);                   // 3200 waves = 25 ki x 128 groups
    if (ws_size >= (size_t)NK * WPT * sizeof(_Float16)) {
        _Float16* wgpT = (_Float16*)d_ws;
        gather_wp<<<(NK * WPT + 255) / 256, 256, 0, stream>>>(W, wgpT);
        lc2d_wave<true><<<grid, 256, 0, stream>>>(x, wgpT, W, bias, out);
    } else {
        lc2d_wave<false><<<grid, 256, 0, stream>>>(x, nullptr, W, bias, out);
    }
}

// Round 14
// 121.715 us; speedup vs baseline: 1.1349x; 1.0370x over previous
//
#include <hip/hip_runtime.h>

typedef _Float16 f16x2 __attribute__((ext_vector_type(2)));
typedef __fp16  fp16x2 __attribute__((ext_vector_type(2)));

// Problem constants
constexpr int NKW  = 25, NK = 625;
constexpr int WPADR = 132;                  // reference padded width
constexpr int WPT   = 160;                  // padded halves per (ki,kj) weight row
constexpr int RST   = 35;                   // LDS row stride in uint2 (+1 anti-conflict)
constexpr int IMG   = 8;                    // images per block (weight reuse factor)
constexpr int NSLAB = 6;                    // ki slabs: NKI = {5,4,4,4,4,4}
constexpr int MAXR  = 30;                   // max staged rows (slab 0)

union U2H { unsigned int u; f16x2 h; fp16x2 p; };

// ---- gather: dense W -> f16 weights, zero-padded 16-slot rows, TRANSPOSED ----
// wgpT as uint4[20][625]; slot j of output k holds padded halves 8j..8j+7.
// Real data at in-row slot o..o+9, o = (5*kj+2) & 3, matching aligned LDS
// window h0 = (5*kj+2) & ~3.
__global__ void gather_wp(const float* __restrict__ W, _Float16* __restrict__ wgpT) {
    int t = blockIdx.x * 256 + threadIdx.x;
    if (t >= NK * WPT) return;
    int k = t / WPT, p = t % WPT;
    int di = p >> 4, s = p & 15;
    int ki = k / NKW, kj = k % NKW;
    int o = (5 * kj + 2) & 3;
    int j = s - o;
    float val = 0.f;
    if (j >= 0 && j < 10)
        val = W[(size_t)((ki * 5 + di) * WPADR + kj * 5 + j) * NK + k];
    wgpT[((size_t)(p >> 3) * NK + k) * 8 + (p & 7)] = (_Float16)val;
}

__device__ __forceinline__ float dot2acc(unsigned int a, unsigned int b, float c) {
    U2H ua, ub; ua.u = a; ub.u = b;
#if __has_builtin(__builtin_amdgcn_fdot2)
    return __builtin_amdgcn_fdot2(ua.h, ub.h, c, false);
#else
    return c + (float)ua.h.x * (float)ub.h.x + (float)ua.h.y * (float)ub.h.y;
#endif
}

// R11 structure + XCD-PINNING SWIZZLE. All 6 ki-slabs of an image group get
// blocks with the same (flat % 8) -> same XCD (dispatch round-robins XCDs),
// so the 1.95x band/halo re-reads of x hit that XCD's L2 instead of L3/HBM.
// (R7-R13 post-mortems: occupancy/pipeline-depth/barriers all neutral; the
// shared limiter is cross-XCD-redundant x traffic, ~131 MB for 64 MB unique.)
template <bool USE_WG>
__global__ __launch_bounds__(256, 4)
void lc2d_pipe(const float* __restrict__ x, const _Float16* __restrict__ wgpT,
               const float* __restrict__ Wfull,
               const float* __restrict__ bias, float* __restrict__ out) {
    __shared__ uint2 xs[2][MAXR * RST];     // 16800 B

    // swizzle: flat -> (grp, slab) with grp % 8 == flat % 8 (XCD-pinned)
    const int flat = blockIdx.x;            // 0..767
    const int xcd  = flat & 7;
    const int j_   = flat >> 3;             // 0..95
    const int grp  = xcd + 8 * (j_ & 15);   // 0..127
    const int slab = j_ >> 4;               // 0..5
    const int K0   = slab ? (4 * slab + 1) : 0;   // 0,5,9,13,17,21
    const int NKI  = slab ? 4 : 5;
    const int R    = 5 * NKI + 5;           // staged rows: 30 / 25
    const int NOUT = NKI * NKW;             // 125 / 100
    const int row0 = 5 * K0 - 2;            // unpadded row of staged idx 0
    const int tid  = threadIdx.x;
    const int b0   = grp * IMG;

    // pair mapping: wave w, lane l -> pair = w*32 + (l&31), half = (l>>5)&1
    const int lane = tid & 63;
    const int pairidx = (tid >> 6) * 32 + (lane & 31);
    const int half = (lane >> 5) & 1;
    const bool active = pairidx < NOUT;
    const int ki_l = pairidx / 25;
    const int kj   = pairidx - ki_l * 25;
    const int k    = (K0 + ki_l) * NKW + kj;
    const int di0  = half * 5;              // this thread's 5 di rows

    // ---- weights: 10 coalesced uint4 per thread, ONCE per block ----
    uint4 wq[10];
    float bval = 0.f;
    if (active) {
        if (USE_WG) {
            const uint4* wt4 = reinterpret_cast<const uint4*>(wgpT);
#pragma unroll
            for (int j = 0; j < 10; ++j) wq[j] = wt4[(size_t)(half * 10 + j) * NK + k];
        } else {
            const int o = (5 * kj + 2) & 3;
#pragma unroll
            for (int j = 0; j < 10; ++j) {
                const int di = di0 + (j >> 1), pb = (j & 1) * 8;
                unsigned int uu[4];
#pragma unroll
                for (int m = 0; m < 4; ++m) {
                    float f0 = 0.f, f1 = 0.f;
                    const int j0 = pb + 2 * m - o, j1 = pb + 2 * m + 1 - o;
                    const size_t rowb = (size_t)(((K0 + ki_l) * 5 + di) * WPADR + kj * 5);
                    if (j0 >= 0 && j0 < 10) f0 = Wfull[(rowb + j0) * NK + k];
                    if (j1 >= 0 && j1 < 10) f1 = Wfull[(rowb + j1) * NK + k];
                    U2H u; u.p = __builtin_amdgcn_cvt_pkrtz(f0, f1);
                    uu[m] = u.u;
                }
                wq[j] = make_uint4(uu[0], uu[1], uu[2], uu[3]);
            }
        }
        if (half == 0) bval = bias[k];
    }

    // ---- boundary zeros, once, both buffers (q=0 left pad, q=33 right pad) ----
    for (int i = tid; i < 4 * R; i += 256)
        xs[i & 1][(i >> 2) * RST + ((i >> 1) & 1) * 33] = make_uint2(0u, 0u);

    // ---- pipeline phases ----
    auto stage_load = [&](int img, float4* tmp) {
        const float* xb = x + ((size_t)(b0 + img) << 14);
#pragma unroll
        for (int t = 0; t < 4; ++t) {
            const int i = tid + t * 256;
            tmp[t] = make_float4(0.f, 0.f, 0.f, 0.f);
            if (i < R * 32) {
                const int idx = i >> 5, q = i & 31;
                const int r = row0 + idx;
                if (r >= 0 && r < 128)
                    tmp[t] = *reinterpret_cast<const float4*>(xb + (r << 7) + (q << 2));
            }
        }
    };
    auto stage_write = [&](int buf, const float4* tmp) {
#pragma unroll
        for (int t = 0; t < 4; ++t) {
            const int i = tid + t * 256;
            if (i < R * 32) {
                const int idx = i >> 5, q = (i & 31) + 1;
                U2H u0, u1;
                u0.p = __builtin_amdgcn_cvt_pkrtz(tmp[t].x, tmp[t].y);
                u1.p = __builtin_amdgcn_cvt_pkrtz(tmp[t].z, tmp[t].w);
                xs[buf][idx * RST + q] = make_uint2(u0.u, u1.u);
            }
        }
    };

    // tmp[j&1] holds image j's loads. Prologue: img0 staged, img1 in flight.
    float4 tmpA[4], tmpB[4];
    stage_load(0, tmpA);
    stage_write(0, tmpA);
    stage_load(1, tmpB);
    __syncthreads();

    for (int i = 0; i < IMG; ++i) {
        // issue image i+2's loads into the tmp slot just freed (image i's)
        if (i + 2 < IMG) stage_load(i + 2, (i & 1) ? tmpB : tmpA);

        float acc0 = 0.f, acc1 = 0.f;
        if (active) {
            const uint2* base = xs[i & 1] + (5 * ki_l + di0) * RST + ((5 * kj + 2) >> 2);
#pragma unroll
            for (int d = 0; d < 5; ++d) {
                const uint2* rowp = base + d * RST;
                const uint2 a0 = rowp[0], a1 = rowp[1], a2 = rowp[2], a3 = rowp[3];
                const uint4 wA = wq[2 * d], wB = wq[2 * d + 1];
                acc0 = dot2acc(a0.x, wA.x, acc0);
                acc1 = dot2acc(a0.y, wA.y, acc1);
                acc0 = dot2acc(a1.x, wA.z, acc0);
                acc1 = dot2acc(a1.y, wA.w, acc1);
                acc0 = dot2acc(a2.x, wB.x, acc0);
                acc1 = dot2acc(a2.y, wB.y, acc1);
                acc0 = dot2acc(a3.x, wB.z, acc0);
                acc1 = dot2acc(a3.y, wB.w, acc1);
            }
        }
        // combine lane pair (l, l^32) within the wave; half 0 stores
        float acc = acc0 + acc1;
        float other = __shfl_xor(acc, 32, 64);
        if (active && half == 0)
            out[(size_t)(b0 + i) * NK + k] = acc + other + bval;

        // write image i+1 into the other LDS buffer; waits only its own loads
        if (i + 1 < IMG) stage_write((i + 1) & 1, (i & 1) ? tmpA : tmpB);
        __syncthreads();
    }
}

extern "C" void kernel_launch(void* const* d_in, const int* in_sizes, int n_in,
                              void* d_out, int out_size, void* d_ws, size_t ws_size,
                              hipStream_t stream) {
    const float* x    = (const float*)d_in[0];
    const float* W    = (const float*)d_in[1];
    const float* bias = (const float*)d_in[2];
    float* out = (float*)d_out;

    const dim3 grid(128 * NSLAB);           // 768 blocks, XCD-swizzled in-kernel
    if (ws_size >= (size_t)NK * WPT * sizeof(_Float16)) {
        _Float16* wgpT = (_Float16*)d_ws;
        gather_wp<<<(NK * WPT + 255) / 256, 256, 0, stream>>>(W, wgpT);
        lc2d_pipe<true><<<grid, 256, 0, stream>>>(x, wgpT, W, bias, out);
    } else {
        lc2d_pipe<false><<<grid, 256, 0, stream>>>(x, nullptr, W, bias, out);
    }
}